// Round 6
// baseline (98.103 us; speedup 1.0000x reference)
//
#include <hip/hip_runtime.h>

// GAPooling: out[b,n,c] = mean_k x[b, idx[b,n,k], c]
// B=16, N=4096, K=32, C=64, fp32. idx int64-or-int32 (runtime-detected).
//
// R6: dual-pipe hybrid. Points [0,PSPLIT) gathered from a 64 KiB LDS tile
// (ds_read_b128, R5 shape); points [PSPLIT,4096) gathered directly from x
// through L1/L2 (coalesced 256B rows, c=lane, R2 shape). Both instruction
// streams come from the same waves, interleaved so the LDS section hides the
// global-gather latency and both pipes run concurrently.
// Grid = 16 b x (16 cp x 2 half) = 512 blocks, 2/CU. bid%8 = b%8 XCD swizzle.

#define BB 16
#define NN 4096
#define KK 32
#define CC 64
#define CCH 4
#define NCHUNK (CC / CCH)            // 16
#define THREADS 512
#define PSPLIT 2560                  // points via LDS pipe
#define PHALF (PSPLIT / 2)           // 1280 per half-block
#define L2PTS (NN - PSPLIT)          // 1536 points via L2 pipe
#define L2_PER_BLOCK (L2PTS / 32)    // 48 (32 blocks per batch)
#define L2_PER_WAVE (L2_PER_BLOCK / 8)  // 6
#define NSTEPS L2_PER_WAVE

// idx values < 4096: if idx is int64 (little-endian), all odd words are 0.
__device__ __forceinline__ int detect_is64(const int* __restrict__ w) {
    int v = w[2 * (threadIdx.x & 63) + 1];
    return (__ballot(v != 0) == 0ULL) ? 1 : 0;
}

__global__ __launch_bounds__(256)
void pack_idx_kernel(const int* __restrict__ idx32,
                     ushort* __restrict__ out16) {
    const int is64 = detect_is64(idx32);
    const int tid = blockIdx.x * blockDim.x + threadIdx.x;
    const int stride = gridDim.x * blockDim.x;
    const int M = BB * NN * KK;
    if (is64) {
        const int4* __restrict__ in = (const int4*)idx32;
        uint* __restrict__ o = (uint*)out16;
        for (int i = tid; i < M / 2; i += stride) {
            int4 v = in[i];
            o[i] = (uint)(v.x & 0xFFFF) | ((uint)(v.z & 0xFFFF) << 16);
        }
    } else {
        const int4* __restrict__ in = (const int4*)idx32;
        uint2* __restrict__ o = (uint2*)out16;
        for (int i = tid; i < M / 4; i += stride) {
            int4 v = in[i];
            o[i] = make_uint2((uint)(v.x & 0xFFFF) | ((uint)(v.y & 0xFFFF) << 16),
                              (uint)(v.z & 0xFFFF) | ((uint)(v.w & 0xFFFF) << 16));
        }
    }
}

__global__ __launch_bounds__(THREADS, 4)
void gapool_hybrid_kernel(const float* __restrict__ x,
                          const ushort* __restrict__ idx16,
                          float* __restrict__ out) {
    __shared__ float4 tile[NN];          // 64 KiB: x[b][n][c0:c0+4]

    const int bid = blockIdx.x;          // g*16 + b
    const int b = bid & 15;
    const int g = bid >> 4;              // 0..31 = (half<<4) | cp
    const int cp = g & (NCHUNK - 1);
    const int half = g >> 4;
    const int c0 = cp * CCH;
    const int tid = threadIdx.x;
    const int wv = tid >> 6;
    const int lane = tid & 63;
    const float s = 1.0f / KK;

    const float* __restrict__ xb = x + (size_t)b * NN * CC;
    float* __restrict__ outb = out + (size_t)b * NN * CC;
    const ushort* __restrict__ idxb = idx16 + (size_t)b * NN * KK;

    // This wave's 6 L2-gathered points.
    const int n2base = PSPLIT + g * L2_PER_BLOCK + wv * L2_PER_WAVE;

    // Prefetch idx of first L2 point (hidden behind staging).
    const uint4* __restrict__ ip0 = (const uint4*)(idxb + (size_t)n2base * KK);
    uint4 a0 = ip0[0], a1 = ip0[1], a2 = ip0[2], a3 = ip0[3];

    // Stage tile: row r's 16B of channels c0..c0+3.
    const float4* __restrict__ xb4 = (const float4*)(xb + c0);
    for (int r = tid; r < NN; r += THREADS) {
        tile[r] = xb4[(size_t)r * (CC / 4)];
    }
    __syncthreads();

#pragma unroll
    for (int t = 0; t < NSTEPS; ++t) {
        // Prefetch next L2 point's idx (one step ahead).
        uint4 b0, b1, b2, b3;
        if (t + 1 < NSTEPS) {
            const uint4* ipn =
                (const uint4*)(idxb + (size_t)(n2base + t + 1) * KK);
            b0 = ipn[0]; b1 = ipn[1]; b2 = ipn[2]; b3 = ipn[3];
        }

        // Issue 32 independent global gathers for current L2 point.
        const uint wg[16] = {a0.x, a0.y, a0.z, a0.w, a1.x, a1.y, a1.z, a1.w,
                             a2.x, a2.y, a2.z, a2.w, a3.x, a3.y, a3.z, a3.w};
        float gv[32];
#pragma unroll
        for (int r = 0; r < 16; ++r) {
            gv[2 * r]     = xb[((wg[r] & 0xFFFFu) << 6) + lane];
            gv[2 * r + 1] = xb[((wg[r] >> 16) << 6) + lane];
        }

        // LDS-gathered point (steps 0..2; t==2 only waves 0..3 — uniform).
        if (t < 3) {
            const int p = tid + t * THREADS;
            if (p < PHALF) {
                const int n = half * PHALF + p;
                const uint4* ip = (const uint4*)(idxb + (size_t)n * KK);
                const uint4 u0 = ip[0], u1 = ip[1], u2 = ip[2], u3 = ip[3];
                const uint w[16] = {u0.x, u0.y, u0.z, u0.w,
                                    u1.x, u1.y, u1.z, u1.w,
                                    u2.x, u2.y, u2.z, u2.w,
                                    u3.x, u3.y, u3.z, u3.w};
                float4 acc0 = make_float4(0.f, 0.f, 0.f, 0.f);
                float4 acc1 = make_float4(0.f, 0.f, 0.f, 0.f);
#pragma unroll
                for (int i = 0; i < 16; ++i) {
                    {
                        const float4 v = tile[w[i] & 0xFFFFu];
                        acc0.x += v.x; acc0.y += v.y;
                        acc0.z += v.z; acc0.w += v.w;
                    }
                    {
                        const float4 v = tile[w[i] >> 16];
                        acc1.x += v.x; acc1.y += v.y;
                        acc1.z += v.z; acc1.w += v.w;
                    }
                }
                const float4 rr = make_float4((acc0.x + acc1.x) * s,
                                              (acc0.y + acc1.y) * s,
                                              (acc0.z + acc1.z) * s,
                                              (acc0.w + acc1.w) * s);
                *(float4*)(outb + (size_t)n * CC + c0) = rr;
            }
        }

        // Consume gathers, store L2 point (coalesced 256B row).
        float acc = 0.f;
#pragma unroll
        for (int r = 0; r < 32; ++r) acc += gv[r];
        outb[(size_t)(n2base + t) * CC + lane] = acc * s;

        if (t + 1 < NSTEPS) { a0 = b0; a1 = b1; a2 = b2; a3 = b3; }
    }
}

extern "C" void kernel_launch(void* const* d_in, const int* in_sizes, int n_in,
                              void* d_out, int out_size, void* d_ws, size_t ws_size,
                              hipStream_t stream) {
    const float* x     = (const float*)d_in[0];
    const int*   idx32 = (const int*)d_in[1];
    float*       out   = (float*)d_out;
    ushort*      idx16 = (ushort*)d_ws;     // 4 MiB of scratch

    pack_idx_kernel<<<1024, 256, 0, stream>>>(idx32, idx16);

    gapool_hybrid_kernel<<<BB * NCHUNK * 2, THREADS, 0, stream>>>(
        x, idx16, out);
}